// Round 9
// baseline (141.185 us; speedup 1.0000x reference)
//
#include <hip/hip_runtime.h>
#include <hip/hip_bf16.h>

// Head: q,k,v = x@W^T+b ; causal softmax(q k^T / 8) @ v
// B=8, T=2048, E=1024, HS=64.
// R9: qkv staging pipelined (R8 post-mortem: qkv's stage->barrier->compute
// phases hard-serialize; ~40-50us vs 15us model).
//   qkv: 4 slabs x 256 cols, double-buffered LDS (33KB). Per slab: issue
//        next slab's global loads -> 8kk MFMA on current -> convert+write
//        next -> 1 barrier. HBM stream overlaps MFMA continuously.
//   attn_part/combine/prep: identical to R8 (S^T trick, chunk=4).

typedef __attribute__((ext_vector_type(8))) short short8;   // 8 bf16 (4 VGPRs)
typedef __attribute__((ext_vector_type(4))) float f32x4;    // MFMA acc

#if __has_builtin(__builtin_amdgcn_exp2f)
#define EXP2(x) __builtin_amdgcn_exp2f(x)
#else
#define EXP2(x) exp2f(x)
#endif

#define QSCALE 0.18033688f   // 0.125 * log2(e)

__device__ inline unsigned short f2bf(float f) {
    unsigned int u = __builtin_bit_cast(unsigned int, f);
    u += 0x7FFF + ((u >> 16) & 1);   // RNE
    return (unsigned short)(u >> 16);
}

// ---------------- Kernel 0: W -> bf16 fragment-major ----------------
__global__ __launch_bounds__(64) void prep_w(
    const float* __restrict__ Wq, const float* __restrict__ Wk,
    const float* __restrict__ Wv, unsigned short* __restrict__ Wfrag)
{
    const int ct = blockIdx.x >> 5;   // 0..11
    const int kk = blockIdx.x & 31;   // 0..31
    const int L  = threadIdx.x;
    const int l16 = L & 15, quad = L >> 4;
    const int col = ct * 16 + l16;    // 0..191

    const float* W; int row; float scale = 1.0f;
    if (col < 64)       { W = Wq; row = col;       scale = QSCALE; }
    else if (col < 128) { W = Wk; row = col - 64; }
    else                { W = Wv; row = col - 128; }

    const float* p = W + (size_t)row * 1024 + kk * 32 + quad * 8;
    alignas(16) unsigned short tmp[8];
    #pragma unroll
    for (int j = 0; j < 8; j++) tmp[j] = f2bf(p[j] * scale);
    unsigned short* dst = Wfrag + ((size_t)blockIdx.x * 64 + L) * 8;
    *reinterpret_cast<int4*>(dst) = *reinterpret_cast<const int4*>(tmp);
}

// ---------------- Kernel 1: QKV projection, slab-pipelined ----------------
// grid 512 x 256 thr. M=32 rows/block. 4 slabs of 256 cols, dbuf LDS.
#define XSLD 260   // slab row stride (elems): 512B data + 8B pad
__global__ __launch_bounds__(256, 2) void qkv_kernel(
    const float* __restrict__ x, const unsigned short* __restrict__ Wfrag,
    const float* __restrict__ bq, const float* __restrict__ bk,
    const float* __restrict__ bv,
    unsigned short* __restrict__ Qb, unsigned short* __restrict__ Kf,
    unsigned short* __restrict__ Vf)
{
    __shared__ alignas(16) unsigned short xs[2][32][XSLD];   // 33.3 KB

    const int tid  = threadIdx.x;
    const int m0   = blockIdx.x * 32;
    const int lane = tid & 63;
    const int w    = tid >> 6;
    const int l16  = lane & 15, quad = lane >> 4;
    const int ct0  = w * 3;

    // staging: per slab 1024 chunks (32 rows x 32 chunks of 8 floats)
    const int sr = (tid * 4) >> 5;        // base row pattern via ch = tid+256i
    (void)sr;

    float4 regs[8];
    // issue slab 0 loads
    #pragma unroll
    for (int i = 0; i < 4; i++) {
        int ch = tid + 256 * i;
        int r = ch >> 5, c8 = ch & 31;
        const float* p = x + (size_t)(m0 + r) * 1024 + c8 * 8;
        regs[2 * i]     = *reinterpret_cast<const float4*>(p);
        regs[2 * i + 1] = *reinterpret_cast<const float4*>(p + 4);
    }

    f32x4 acc[2][3];
    #pragma unroll
    for (int a = 0; a < 2; a++)
        #pragma unroll
        for (int c = 0; c < 3; c++) acc[a][c] = (f32x4){0.f, 0.f, 0.f, 0.f};

    // B-frag prefetch init (kk = 0)
    short8 bcur[3];
    #pragma unroll
    for (int ci = 0; ci < 3; ci++)
        bcur[ci] = *reinterpret_cast<const short8*>(
            Wfrag + ((size_t)((ct0 + ci) * 32) * 64 + lane) * 8);

    // write slab 0
    #pragma unroll
    for (int i = 0; i < 4; i++) {
        int ch = tid + 256 * i;
        int r = ch >> 5, c8 = ch & 31;
        float4 v0 = regs[2 * i], v1 = regs[2 * i + 1];
        alignas(16) unsigned short t8[8] = {
            f2bf(v0.x), f2bf(v0.y), f2bf(v0.z), f2bf(v0.w),
            f2bf(v1.x), f2bf(v1.y), f2bf(v1.z), f2bf(v1.w)};
        *reinterpret_cast<int4*>(&xs[0][r][c8 * 8]) =
            *reinterpret_cast<const int4*>(t8);
    }
    __syncthreads();

    for (int s = 0; s < 4; s++) {
        // issue next slab's global loads (overlap with this slab's MFMAs)
        if (s < 3) {
            #pragma unroll
            for (int i = 0; i < 4; i++) {
                int ch = tid + 256 * i;
                int r = ch >> 5, c8 = ch & 31;
                const float* p = x + (size_t)(m0 + r) * 1024 + (s + 1) * 256 + c8 * 8;
                regs[2 * i]     = *reinterpret_cast<const float4*>(p);
                regs[2 * i + 1] = *reinterpret_cast<const float4*>(p + 4);
            }
        }

        const int buf = s & 1;
        #pragma unroll
        for (int kk2 = 0; kk2 < 8; kk2++) {
            const int kk  = s * 8 + kk2;
            const int kkn = (kk < 31) ? kk + 1 : 31;
            short8 bnxt[3];
            #pragma unroll
            for (int ci = 0; ci < 3; ci++)
                bnxt[ci] = *reinterpret_cast<const short8*>(
                    Wfrag + ((size_t)((ct0 + ci) * 32 + kkn) * 64 + lane) * 8);

            short8 a0 = *reinterpret_cast<const short8*>(
                &xs[buf][l16][kk2 * 32 + quad * 8]);
            short8 a1 = *reinterpret_cast<const short8*>(
                &xs[buf][16 + l16][kk2 * 32 + quad * 8]);
            #pragma unroll
            for (int ci = 0; ci < 3; ci++) {
                acc[0][ci] = __builtin_amdgcn_mfma_f32_16x16x32_bf16(a0, bcur[ci], acc[0][ci], 0, 0, 0);
                acc[1][ci] = __builtin_amdgcn_mfma_f32_16x16x32_bf16(a1, bcur[ci], acc[1][ci], 0, 0, 0);
            }
            #pragma unroll
            for (int ci = 0; ci < 3; ci++) bcur[ci] = bnxt[ci];
        }

        if (s < 3) {
            // convert + write next slab into the other buffer, then barrier.
            // (barrier after write separates this write from lagging waves'
            //  reads of the same buffer in the previous slab: any writer has
            //  passed the previous barrier, so all readers are done.)
            #pragma unroll
            for (int i = 0; i < 4; i++) {
                int ch = tid + 256 * i;
                int r = ch >> 5, c8 = ch & 31;
                float4 v0 = regs[2 * i], v1 = regs[2 * i + 1];
                alignas(16) unsigned short t8[8] = {
                    f2bf(v0.x), f2bf(v0.y), f2bf(v0.z), f2bf(v0.w),
                    f2bf(v1.x), f2bf(v1.y), f2bf(v1.z), f2bf(v1.w)};
                *reinterpret_cast<int4*>(&xs[buf ^ 1][r][c8 * 8]) =
                    *reinterpret_cast<const int4*>(t8);
            }
            __syncthreads();
        }
    }

    // epilogue: C/D layout col=lane&15, row=(lane>>4)*4+i
    const int bi = m0 >> 11;
    #pragma unroll
    for (int rt = 0; rt < 2; rt++) {
        #pragma unroll
        for (int ci = 0; ci < 3; ci++) {
            const int ct = ct0 + ci;
            const int h  = (ct & 3) * 16 + l16;
            if (ct < 4) {
                float bias = bq[h] * QSCALE;
                #pragma unroll
                for (int i = 0; i < 4; i++) {
                    size_t m = (size_t)(m0 + rt * 16 + quad * 4 + i);
                    Qb[m * 64 + h] = f2bf(acc[rt][ci][i] + bias);
                }
            } else if (ct < 8) {
                // K -> B-frag-major (8 consecutive l16 lanes = 16B contiguous)
                float bias = bk[h];
                #pragma unroll
                for (int i = 0; i < 4; i++) {
                    int t   = m0 + rt * 16 + quad * 4 + i;
                    int tin = t & 63;
                    int kt  = (t & 2047) >> 6;
                    int f   = ((h >> 5) << 2) | (tin >> 4);
                    int lp  = (tin & 15) | (((h >> 3) & 3) << 4);
                    Kf[(((size_t)(bi * 32 + kt) * 8 + f) * 64 + lp) * 8 + (h & 7)]
                        = f2bf(acc[rt][ci][i] + bias);
                }
            } else {
                // V -> B-frag-major; i=0..3 pack into one 8B store
                float bias = bv[h];
                int tb  = m0 + rt * 16 + quad * 4;
                int tin = tb & 63;
                int kt  = (tb & 2047) >> 6;
                int f   = ((tin >> 5) << 2) | (h >> 4);
                int lp  = (h & 15) | (((tin >> 3) & 3) << 4);
                alignas(8) unsigned short tmp[4];
                #pragma unroll
                for (int i = 0; i < 4; i++) tmp[i] = f2bf(acc[rt][ci][i] + bias);
                unsigned short* dst =
                    Vf + (((size_t)(bi * 32 + kt) * 8 + f) * 64 + lp) * 8 + (tin & 7);
                *reinterpret_cast<int2*>(dst) = *reinterpret_cast<const int2*>(tmp);
            }
        }
    }
}

// ---------------- Kernel 2: flash attention, split-K partials ----------------
// grid 2048 = c(8, slowest) x j64(32) x batch(8); chunk = 4 k-tiles.
// 4 waves = 4 q-tiles sharing one (b, chunk). S^T layout: qr on l16.
__global__ __launch_bounds__(256, 4) void attn_part(
    const unsigned short* __restrict__ Qb,
    const unsigned short* __restrict__ Kf,
    const unsigned short* __restrict__ Vf,
    float* __restrict__ Opart, float* __restrict__ Lpart)
{
    __shared__ alignas(16) unsigned short ps[4][16][72];

    const int bid = blockIdx.x;
    const int b   = bid & 7;
    const int j64 = (bid >> 3) & 31;
    const int c   = bid >> 8;            // 0..7
    const int nkt = j64 + 1;
    const int kt0 = c * 4;
    if (kt0 >= nkt) return;
    const int kt1 = (kt0 + 4 < nkt) ? kt0 + 4 : nkt;

    const int tid  = threadIdx.x;
    const int w    = tid >> 6;
    const int lane = tid & 63;
    const int l16  = lane & 15, quad = lane >> 4;
    const int j16  = j64 * 4 + w;
    const int q0   = j16 * 16;

    const unsigned short* qrow = Qb + ((size_t)(b * 2048 + q0 + l16)) * 64 + quad * 8;
    short8 aq0 = *reinterpret_cast<const short8*>(qrow);
    short8 aq1 = *reinterpret_cast<const short8*>(qrow + 32);

    const unsigned short* Kbat = Kf + (size_t)(b * 32) * 4096;
    const unsigned short* Vbat = Vf + (size_t)(b * 32) * 4096;

    f32x4 o[4];
    float rs = 0.f;                       // per-lane; row = l16 (S^T layout)
    #pragma unroll
    for (int i = 0; i < 4; i++) o[i] = (f32x4){0, 0, 0, 0};

    for (int kt = kt0; kt < kt1; kt++) {
        // K + V frags: 1KB contiguous loads, L1-shared across the 4 waves
        short8 kfr[8], vfr[8];
        {
            const unsigned short* kb = Kbat + (size_t)kt * 4096 + lane * 8;
            const unsigned short* vb = Vbat + (size_t)kt * 4096 + lane * 8;
            #pragma unroll
            for (int f = 0; f < 8; f++) {
                kfr[f] = *reinterpret_cast<const short8*>(kb + f * 512);
                vfr[f] = *reinterpret_cast<const short8*>(vb + f * 512);
            }
        }

        // S^T = K Q^T (A=K-frag, B=Q-frag; identical frag layouts).
        // D: col(l16)=qr, row(quad*4+i)=kc_local = ct*16+quad*4+i.
        f32x4 s[4];
        #pragma unroll
        for (int ct = 0; ct < 4; ct++) s[ct] = (f32x4){0, 0, 0, 0};
        #pragma unroll
        for (int ks2 = 0; ks2 < 2; ks2++) {
            short8 aqf = ks2 ? aq1 : aq0;
            #pragma unroll
            for (int ct = 0; ct < 4; ct++)
                s[ct] = __builtin_amdgcn_mfma_f32_16x16x32_bf16(
                    kfr[ks2 * 4 + ct], aqf, s[ct], 0, 0, 0);
        }

        // causal mask on diagonal k-tile: kc > qr -> -inf
        if (kt == nkt - 1) {
            const int qr = q0 + l16;
            #pragma unroll
            for (int ct = 0; ct < 4; ct++) {
                #pragma unroll
                for (int i = 0; i < 4; i++) {
                    int kc = kt * 64 + ct * 16 + quad * 4 + i;
                    if (kc > qr) s[ct][i] = -1e30f;
                }
            }
        }

        // P = exp2(S^T); per-lane row-sum (row fixed = l16); pack 4 -> b64
        #pragma unroll
        for (int ct = 0; ct < 4; ct++) {
            alignas(8) unsigned short t4[4];
            #pragma unroll
            for (int i = 0; i < 4; i++) {
                float p = EXP2(s[ct][i]);
                rs += p;
                t4[i] = f2bf(p);
            }
            *reinterpret_cast<int2*>(&ps[w][l16][ct * 16 + quad * 4]) =
                *reinterpret_cast<const int2*>(t4);
        }

        // A-frag read: P[qr=l16][kc contiguous] (per-wave DS ordering)
        short8 ap0 = *reinterpret_cast<const short8*>(&ps[w][l16][quad * 8]);
        short8 ap1 = *reinterpret_cast<const short8*>(&ps[w][l16][32 + quad * 8]);

        #pragma unroll
        for (int ks2 = 0; ks2 < 2; ks2++) {
            short8 apf = ks2 ? ap1 : ap0;
            #pragma unroll
            for (int ct = 0; ct < 4; ct++)
                o[ct] = __builtin_amdgcn_mfma_f32_16x16x32_bf16(
                    apf, vfr[ks2 * 4 + ct], o[ct], 0, 0, 0);
        }
    }

    // partials: unnormalized O + row sums l; slot pid = (c,j16,b)
    const int pid = (c << 10) | (j16 << 3) | b;
    float* op = Opart + (size_t)pid * 1024;
    #pragma unroll
    for (int i = 0; i < 4; i++) {
        int r = quad * 4 + i;
        #pragma unroll
        for (int ct = 0; ct < 4; ct++)
            op[(size_t)r * 64 + ct * 16 + l16] = o[ct][i];
    }
    // reduce row-sums across the 4 quads holding the same l16 row
    float v = rs;
    v += __shfl_xor(v, 16);
    v += __shfl_xor(v, 32);
    if (quad == 0) Lpart[(size_t)pid * 16 + l16] = v;
}

// ---------------- Kernel 3: combine ----------------
__global__ __launch_bounds__(256) void attn_combine(
    const float* __restrict__ Opart, const float* __restrict__ Lpart,
    float* __restrict__ out)
{
    const int t0 = blockIdx.x * 256 + threadIdx.x;
    #pragma unroll
    for (int it = 0; it < 2; it++) {
        const int v    = t0 + it * 131072;
        const int flat = v * 4;
        const int b    = flat >> 17;
        const int rem  = flat & 131071;
        const int t    = rem >> 6;
        const int h0   = rem & 63;
        const int j16  = t >> 4, row = t & 15;
        const int nch  = ((j16 >> 2) + 4) >> 2;    // ceil(nkt/4), 1..8
        const int pidb = (j16 << 3) | b;

        float4 acc = {0.f, 0.f, 0.f, 0.f};
        float  l   = 0.f;
        for (int c = 0; c < nch; c++) {
            const int pid = (c << 10) | pidb;
            const float* op = Opart + (size_t)pid * 1024 + row * 64 + h0;
            float4 x4 = *reinterpret_cast<const float4*>(op);
            acc.x += x4.x; acc.y += x4.y; acc.z += x4.z; acc.w += x4.w;
            l += Lpart[(size_t)pid * 16 + row];
        }
        const float inv = 1.f / l;
        float4 r = {acc.x * inv, acc.y * inv, acc.z * inv, acc.w * inv};
        *reinterpret_cast<float4*>(out + flat) = r;
    }
}

extern "C" void kernel_launch(void* const* d_in, const int* in_sizes, int n_in,
                              void* d_out, int out_size, void* d_ws, size_t ws_size,
                              hipStream_t stream) {
    const float* x  = (const float*)d_in[0];
    const float* Wq = (const float*)d_in[1];
    const float* bq = (const float*)d_in[2];
    const float* Wk = (const float*)d_in[3];
    const float* bk = (const float*)d_in[4];
    const float* Wv = (const float*)d_in[5];
    const float* bv = (const float*)d_in[6];
    float* out = (float*)d_out;

    unsigned short* Qb    = (unsigned short*)d_ws;            // [16384][64] bf16
    unsigned short* Kf    = Qb + (size_t)16384 * 64;          // [8][32][8][64][8]
    unsigned short* Vf    = Kf + (size_t)16384 * 64;          // [8][32][8][64][8]
    unsigned short* Wfrag = Vf + (size_t)16384 * 64;          // [12][32][64][8]
    float* Opart = (float*)(Wfrag + (size_t)12 * 32 * 64 * 8); // [8192][16][64] f32
    float* Lpart = Opart + (size_t)8192 * 1024;               // [8192][16] f32

    prep_w<<<384, 64, 0, stream>>>(Wq, Wk, Wv, Wfrag);
    qkv_kernel<<<512, 256, 0, stream>>>(x, Wfrag, bq, bk, bv, Qb, Kf, Vf);
    attn_part<<<2048, 256, 0, stream>>>(Qb, Kf, Vf, Opart, Lpart);
    attn_combine<<<512, 256, 0, stream>>>(Opart, Lpart, out);
}

// Round 10
// 134.346 us; speedup vs baseline: 1.0509x; 1.0509x over previous
//
#include <hip/hip_runtime.h>
#include <hip/hip_bf16.h>

// Head: q,k,v = x@W^T+b ; causal softmax(q k^T / 8) @ v
// B=8, T=2048, E=1024, HS=64.
// R10: qkv = R8 form (best measured; R7/R9 pipelining variants regressed).
//   attn_part: cooperative K/V staging via __builtin_amdgcn_global_load_lds
//   (frag-major layout == wave-uniform base + lane*16B, DMA-perfect).
//   Double-buffered 32KB LDS, 1 barrier/k-tile, frags via ds_read_b128.
//   4x less L1/L2 K/V traffic, ~60 fewer VGPRs than R8.

typedef __attribute__((ext_vector_type(8))) short short8;   // 8 bf16 (4 VGPRs)
typedef __attribute__((ext_vector_type(4))) float f32x4;    // MFMA acc

#if __has_builtin(__builtin_amdgcn_exp2f)
#define EXP2(x) __builtin_amdgcn_exp2f(x)
#else
#define EXP2(x) exp2f(x)
#endif

#define QSCALE 0.18033688f   // 0.125 * log2(e)

__device__ inline unsigned short f2bf(float f) {
    unsigned int u = __builtin_bit_cast(unsigned int, f);
    u += 0x7FFF + ((u >> 16) & 1);   // RNE
    return (unsigned short)(u >> 16);
}

__device__ inline void load_lds16(const void* g, void* l) {
    __builtin_amdgcn_global_load_lds(
        (const __attribute__((address_space(1))) void*)g,
        (__attribute__((address_space(3))) void*)l, 16, 0, 0);
}

// ---------------- Kernel 0: W -> bf16 fragment-major ----------------
__global__ __launch_bounds__(64) void prep_w(
    const float* __restrict__ Wq, const float* __restrict__ Wk,
    const float* __restrict__ Wv, unsigned short* __restrict__ Wfrag)
{
    const int ct = blockIdx.x >> 5;   // 0..11
    const int kk = blockIdx.x & 31;   // 0..31
    const int L  = threadIdx.x;
    const int l16 = L & 15, quad = L >> 4;
    const int col = ct * 16 + l16;    // 0..191

    const float* W; int row; float scale = 1.0f;
    if (col < 64)       { W = Wq; row = col;       scale = QSCALE; }
    else if (col < 128) { W = Wk; row = col - 64; }
    else                { W = Wv; row = col - 128; }

    const float* p = W + (size_t)row * 1024 + kk * 32 + quad * 8;
    alignas(16) unsigned short tmp[8];
    #pragma unroll
    for (int j = 0; j < 8; j++) tmp[j] = f2bf(p[j] * scale);
    unsigned short* dst = Wfrag + ((size_t)blockIdx.x * 64 + L) * 8;
    *reinterpret_cast<int4*>(dst) = *reinterpret_cast<const int4*>(tmp);
}

// ---------------- Kernel 1: QKV projection (R8/R6 form) ----------------
#define XLD 1032
__global__ __launch_bounds__(256, 4) void qkv_kernel(
    const float* __restrict__ x, const unsigned short* __restrict__ Wfrag,
    const float* __restrict__ bq, const float* __restrict__ bk,
    const float* __restrict__ bv,
    unsigned short* __restrict__ Qb, unsigned short* __restrict__ Kf,
    unsigned short* __restrict__ Vf)
{
    __shared__ alignas(16) unsigned short xs[32][XLD];   // 64.5 KB

    const int tid  = threadIdx.x;
    const int m0   = blockIdx.x * 32;
    const int lane = tid & 63;
    const int w    = tid >> 6;
    const int l16  = lane & 15, quad = lane >> 4;

    // stage x[32][1024] fp32 -> bf16 LDS, flat 16B-chunk mapping
    #pragma unroll
    for (int i = 0; i < 16; i++) {
        int ch  = tid + 256 * i;
        int r   = ch >> 7;
        int c16 = ch & 127;
        const float* p = x + (size_t)(m0 + r) * 1024 + c16 * 8;
        float4 v0 = *reinterpret_cast<const float4*>(p);
        float4 v1 = *reinterpret_cast<const float4*>(p + 4);
        alignas(16) unsigned short t8[8] = {
            f2bf(v0.x), f2bf(v0.y), f2bf(v0.z), f2bf(v0.w),
            f2bf(v1.x), f2bf(v1.y), f2bf(v1.z), f2bf(v1.w)};
        *reinterpret_cast<int4*>(&xs[r][c16 * 8]) =
            *reinterpret_cast<const int4*>(t8);
    }
    __syncthreads();

    const int ct0 = w * 3;
    f32x4 acc[2][3];
    #pragma unroll
    for (int a = 0; a < 2; a++)
        #pragma unroll
        for (int c = 0; c < 3; c++) acc[a][c] = (f32x4){0.f, 0.f, 0.f, 0.f};

    short8 bcur[3];
    #pragma unroll
    for (int ci = 0; ci < 3; ci++)
        bcur[ci] = *reinterpret_cast<const short8*>(
            Wfrag + ((size_t)((ct0 + ci) * 32) * 64 + lane) * 8);

    for (int kk = 0; kk < 32; kk++) {
        const int kkn = (kk < 31) ? kk + 1 : 31;
        short8 bnxt[3];
        #pragma unroll
        for (int ci = 0; ci < 3; ci++)
            bnxt[ci] = *reinterpret_cast<const short8*>(
                Wfrag + ((size_t)((ct0 + ci) * 32 + kkn) * 64 + lane) * 8);

        short8 a0 = *reinterpret_cast<const short8*>(&xs[l16][kk * 32 + quad * 8]);
        short8 a1 = *reinterpret_cast<const short8*>(&xs[16 + l16][kk * 32 + quad * 8]);
        #pragma unroll
        for (int ci = 0; ci < 3; ci++) {
            acc[0][ci] = __builtin_amdgcn_mfma_f32_16x16x32_bf16(a0, bcur[ci], acc[0][ci], 0, 0, 0);
            acc[1][ci] = __builtin_amdgcn_mfma_f32_16x16x32_bf16(a1, bcur[ci], acc[1][ci], 0, 0, 0);
        }
        #pragma unroll
        for (int ci = 0; ci < 3; ci++) bcur[ci] = bnxt[ci];
    }

    // epilogue: C/D layout col=lane&15, row=(lane>>4)*4+i
    const int bi = m0 >> 11;
    #pragma unroll
    for (int rt = 0; rt < 2; rt++) {
        #pragma unroll
        for (int ci = 0; ci < 3; ci++) {
            const int ct = ct0 + ci;
            const int h  = (ct & 3) * 16 + l16;
            if (ct < 4) {
                float bias = bq[h] * QSCALE;
                #pragma unroll
                for (int i = 0; i < 4; i++) {
                    size_t m = (size_t)(m0 + rt * 16 + quad * 4 + i);
                    Qb[m * 64 + h] = f2bf(acc[rt][ci][i] + bias);
                }
            } else if (ct < 8) {
                // K -> B-frag-major (8 consecutive l16 lanes = 16B contiguous)
                float bias = bk[h];
                #pragma unroll
                for (int i = 0; i < 4; i++) {
                    int t   = m0 + rt * 16 + quad * 4 + i;
                    int tin = t & 63;
                    int kt  = (t & 2047) >> 6;
                    int f   = ((h >> 5) << 2) | (tin >> 4);
                    int lp  = (tin & 15) | (((h >> 3) & 3) << 4);
                    Kf[(((size_t)(bi * 32 + kt) * 8 + f) * 64 + lp) * 8 + (h & 7)]
                        = f2bf(acc[rt][ci][i] + bias);
                }
            } else {
                // V -> B-frag-major; i=0..3 pack into one 8B store
                float bias = bv[h];
                int tb  = m0 + rt * 16 + quad * 4;
                int tin = tb & 63;
                int kt  = (tb & 2047) >> 6;
                int f   = ((tin >> 5) << 2) | (h >> 4);
                int lp  = (h & 15) | (((tin >> 3) & 3) << 4);
                alignas(8) unsigned short tmp[4];
                #pragma unroll
                for (int i = 0; i < 4; i++) tmp[i] = f2bf(acc[rt][ci][i] + bias);
                unsigned short* dst =
                    Vf + (((size_t)(bi * 32 + kt) * 8 + f) * 64 + lp) * 8 + (tin & 7);
                *reinterpret_cast<int2*>(dst) = *reinterpret_cast<const int2*>(tmp);
            }
        }
    }
}

// ---------------- Kernel 2: flash attention, split-K partials ----------------
// grid 2048 = c(8) x j64(32) x batch(8); chunk = 4 k-tiles; 4 waves = 4
// q-tiles sharing one (b, chunk). K/V tile cooperatively DMA'd to LDS via
// global_load_lds (4 frags/wave), double-buffered, 1 barrier per k-tile.
__global__ __launch_bounds__(256) void attn_part(
    const unsigned short* __restrict__ Qb,
    const unsigned short* __restrict__ Kf,
    const unsigned short* __restrict__ Vf,
    float* __restrict__ Opart, float* __restrict__ Lpart)
{
    __shared__ alignas(16) unsigned short kv[2][16][64][8];  // 32 KB (K=f0..7, V=f8..15)
    __shared__ alignas(16) unsigned short ps[4][16][72];     // 9 KB, per-wave

    const int bid = blockIdx.x;
    const int b   = bid & 7;
    const int j64 = (bid >> 3) & 31;
    const int c   = bid >> 8;            // 0..7
    const int nkt = j64 + 1;             // same for all 4 waves of the block
    const int kt0 = c * 4;
    if (kt0 >= nkt) return;              // uniform across block
    const int kt1 = (kt0 + 4 < nkt) ? kt0 + 4 : nkt;

    const int tid  = threadIdx.x;
    const int w    = tid >> 6;
    const int lane = tid & 63;
    const int l16  = lane & 15, quad = lane >> 4;
    const int j16  = j64 * 4 + w;
    const int q0   = j16 * 16;

    const unsigned short* qrow = Qb + ((size_t)(b * 2048 + q0 + l16)) * 64 + quad * 8;
    short8 aq0 = *reinterpret_cast<const short8*>(qrow);
    short8 aq1 = *reinterpret_cast<const short8*>(qrow + 32);

    const unsigned short* Kbat = Kf + (size_t)(b * 32) * 4096;
    const unsigned short* Vbat = Vf + (size_t)(b * 32) * 4096;

    f32x4 o[4];
    float rs = 0.f;                       // per-lane; row = l16 (S^T layout)
    #pragma unroll
    for (int i = 0; i < 4; i++) o[i] = (f32x4){0, 0, 0, 0};

    // cooperative stage of one k-tile: wave w DMAs frags {4w..4w+3}
    // lds dst is wave-uniform; HW scatters lane*16B -> kv[buf][f][lane][0..7]
    #define STAGE_KT(ktv, bufv)                                             \
        {                                                                   \
            _Pragma("unroll")                                               \
            for (int j = 0; j < 4; j++) {                                   \
                int f = w * 4 + j;                                          \
                const unsigned short* src =                                 \
                    (f < 8 ? Kbat + (size_t)(ktv) * 4096 + f * 512          \
                           : Vbat + (size_t)(ktv) * 4096 + (f - 8) * 512)   \
                    + lane * 8;                                             \
                load_lds16(src, &kv[bufv][f][0][0]);                        \
            }                                                               \
        }

    STAGE_KT(kt0, 0);
    __syncthreads();   // drains the DMA (vmcnt) + syncs waves

    for (int kt = kt0; kt < kt1; kt++) {
        const int buf = (kt - kt0) & 1;
        if (kt + 1 < kt1) STAGE_KT(kt + 1, buf ^ 1);

        // S^T = K Q^T (A=K-frag from LDS, B=Q-frag; identical frag layouts)
        // D: col(l16)=qr, row(quad*4+i)=kc_local
        f32x4 s[4];
        #pragma unroll
        for (int ct = 0; ct < 4; ct++) s[ct] = (f32x4){0, 0, 0, 0};
        #pragma unroll
        for (int ks2 = 0; ks2 < 2; ks2++) {
            short8 aqf = ks2 ? aq1 : aq0;
            #pragma unroll
            for (int ct = 0; ct < 4; ct++) {
                short8 kf8 = *reinterpret_cast<const short8*>(
                    &kv[buf][ks2 * 4 + ct][lane][0]);
                s[ct] = __builtin_amdgcn_mfma_f32_16x16x32_bf16(
                    kf8, aqf, s[ct], 0, 0, 0);
            }
        }

        // causal mask on diagonal k-tile: kc > qr -> -inf
        if (kt == nkt - 1) {
            const int qr = q0 + l16;
            #pragma unroll
            for (int ct = 0; ct < 4; ct++) {
                #pragma unroll
                for (int i = 0; i < 4; i++) {
                    int kc = kt * 64 + ct * 16 + quad * 4 + i;
                    if (kc > qr) s[ct][i] = -1e30f;
                }
            }
        }

        // P = exp2(S^T); per-lane row-sum (row fixed = l16); pack 4 -> b64
        #pragma unroll
        for (int ct = 0; ct < 4; ct++) {
            alignas(8) unsigned short t4[4];
            #pragma unroll
            for (int i = 0; i < 4; i++) {
                float p = EXP2(s[ct][i]);
                rs += p;
                t4[i] = f2bf(p);
            }
            *reinterpret_cast<int2*>(&ps[w][l16][ct * 16 + quad * 4]) =
                *reinterpret_cast<const int2*>(t4);
        }

        // A-frag read: P[qr=l16][kc contiguous] (per-wave DS ordering)
        short8 ap0 = *reinterpret_cast<const short8*>(&ps[w][l16][quad * 8]);
        short8 ap1 = *reinterpret_cast<const short8*>(&ps[w][l16][32 + quad * 8]);

        #pragma unroll
        for (int ks2 = 0; ks2 < 2; ks2++) {
            short8 apf = ks2 ? ap1 : ap0;
            #pragma unroll
            for (int ct = 0; ct < 4; ct++) {
                short8 vf8 = *reinterpret_cast<const short8*>(
                    &kv[buf][8 + ks2 * 4 + ct][lane][0]);
                o[ct] = __builtin_amdgcn_mfma_f32_16x16x32_bf16(
                    apf, vf8, o[ct], 0, 0, 0);
            }
        }

        if (kt + 1 < kt1) __syncthreads();  // next-buf DMA done; buf reusable
    }

    // partials: unnormalized O + row sums l; slot pid = (c,j16,b)
    const int pid = (c << 10) | (j16 << 3) | b;
    float* op = Opart + (size_t)pid * 1024;
    #pragma unroll
    for (int i = 0; i < 4; i++) {
        int r = quad * 4 + i;
        #pragma unroll
        for (int ct = 0; ct < 4; ct++)
            op[(size_t)r * 64 + ct * 16 + l16] = o[ct][i];
    }
    // reduce row-sums across the 4 quads holding the same l16 row
    float v = rs;
    v += __shfl_xor(v, 16);
    v += __shfl_xor(v, 32);
    if (quad == 0) Lpart[(size_t)pid * 16 + l16] = v;
}

// ---------------- Kernel 3: combine ----------------
__global__ __launch_bounds__(256) void attn_combine(
    const float* __restrict__ Opart, const float* __restrict__ Lpart,
    float* __restrict__ out)
{
    const int t0 = blockIdx.x * 256 + threadIdx.x;
    #pragma unroll
    for (int it = 0; it < 2; it++) {
        const int v    = t0 + it * 131072;
        const int flat = v * 4;
        const int b    = flat >> 17;
        const int rem  = flat & 131071;
        const int t    = rem >> 6;
        const int h0   = rem & 63;
        const int j16  = t >> 4, row = t & 15;
        const int nch  = ((j16 >> 2) + 4) >> 2;    // ceil(nkt/4), 1..8
        const int pidb = (j16 << 3) | b;

        float4 acc = {0.f, 0.f, 0.f, 0.f};
        float  l   = 0.f;
        for (int c = 0; c < nch; c++) {
            const int pid = (c << 10) | pidb;
            const float* op = Opart + (size_t)pid * 1024 + row * 64 + h0;
            float4 x4 = *reinterpret_cast<const float4*>(op);
            acc.x += x4.x; acc.y += x4.y; acc.z += x4.z; acc.w += x4.w;
            l += Lpart[(size_t)pid * 16 + row];
        }
        const float inv = 1.f / l;
        float4 r = {acc.x * inv, acc.y * inv, acc.z * inv, acc.w * inv};
        *reinterpret_cast<float4*>(out + flat) = r;
    }
}

extern "C" void kernel_launch(void* const* d_in, const int* in_sizes, int n_in,
                              void* d_out, int out_size, void* d_ws, size_t ws_size,
                              hipStream_t stream) {
    const float* x  = (const float*)d_in[0];
    const float* Wq = (const float*)d_in[1];
    const float* bq = (const float*)d_in[2];
    const float* Wk = (const float*)d_in[3];
    const float* bk = (const float*)d_in[4];
    const float* Wv = (const float*)d_in[5];
    const float* bv = (const float*)d_in[6];
    float* out = (float*)d_out;

    unsigned short* Qb    = (unsigned short*)d_ws;            // [16384][64] bf16
    unsigned short* Kf    = Qb + (size_t)16384 * 64;          // [8][32][8][64][8]
    unsigned short* Vf    = Kf + (size_t)16384 * 64;          // [8][32][8][64][8]
    unsigned short* Wfrag = Vf + (size_t)16384 * 64;          // [12][32][64][8]
    float* Opart = (float*)(Wfrag + (size_t)12 * 32 * 64 * 8); // [8192][16][64] f32
    float* Lpart = Opart + (size_t)8192 * 1024;               // [8192][16] f32

    prep_w<<<384, 64, 0, stream>>>(Wq, Wk, Wv, Wfrag);
    qkv_kernel<<<512, 256, 0, stream>>>(x, Wfrag, bq, bk, bv, Qb, Kf, Vf);
    attn_part<<<2048, 256, 0, stream>>>(Qb, Kf, Vf, Opart, Lpart);
    attn_combine<<<512, 256, 0, stream>>>(Opart, Lpart, out);
}